// Round 5
// baseline (548.785 us; speedup 1.0000x reference)
//
#include <hip/hip_runtime.h>

#define NV 400000
#define KOFF 27
#define CD 64
#define DD 128
#define HH 128
#define WW 128
#define TABN (2*DD*HH*WW)
#define EPSV 1e-5f

typedef _Float16 f16;
typedef _Float16 f16x8 __attribute__((ext_vector_type(8)));
typedef float f32x16 __attribute__((ext_vector_type(16)));

// ---- workspace layout (bytes) ----
#define OFF_NBR   0ull
#define OFF_X1    43200000ull
#define OFF_X2    94400000ull
#define OFF_TAB   94400000ull     // table dead before x2 written
#define OFF_W2T   145600000ull
#define OFF_W3T   145821184ull
#define OFF_ZERO  146042368ull

#define GLDS16(gp, lp) __builtin_amdgcn_global_load_lds( \
    (__attribute__((address_space(1))) void*)(gp), \
    (__attribute__((address_space(3))) void*)(lp), 16, 0, 0)

// ---- init: table=-1; weights -> f16 chunk-major wTg[k][cin/8][cout][cin&7]; zero row
__global__ void k_init(const float* __restrict__ w2, const float* __restrict__ w3,
                       int* __restrict__ tab, f16* __restrict__ w2t,
                       f16* __restrict__ w3t, f16* __restrict__ zrow) {
    int t = blockIdx.x * 256 + threadIdx.x;           // grid: 4096*256
    int4* tv = (int4*)tab;
    if (t < TABN / 4) tv[t] = make_int4(-1, -1, -1, -1);
    if (t < KOFF * CD * CD) {
        int k = t >> 12, r = t & 4095, c = r >> 6, ci = r & 63;
        int d = (k << 12) + ((ci >> 3) << 9) + (c << 3) + (ci & 7);
        w2t[d] = (f16)w2[(k << 12) + (ci << 6) + c];
        w3t[d] = (f16)w3[(k << 12) + (ci << 6) + c];
    }
    if (t < CD) zrow[t] = (f16)0.f;
}

__global__ void k_scatter(const int4* __restrict__ coords, int* __restrict__ tab) {
    int i = blockIdx.x * 256 + threadIdx.x;
    if (i >= NV) return;
    int4 c = coords[i];  // (b,z,y,x)
    int flat = ((c.x * DD + c.y) * HH + c.z) * WW + c.w;
    tab[flat] = i;
}

__global__ void k_nbr(const int4* __restrict__ coords, const int* __restrict__ tab,
                      int* __restrict__ nbr) {
    int i = blockIdx.x * 256 + threadIdx.x;
    if (i >= NV) return;
    int4 c = coords[i];
    int k = 0;
    #pragma unroll
    for (int dz = -1; dz <= 1; dz++)
    #pragma unroll
    for (int dy = -1; dy <= 1; dy++)
    #pragma unroll
    for (int dx = -1; dx <= 1; dx++) {
        int z = c.y + dz, y = c.z + dy, x = c.w + dx;
        int idx = -1;
        if (z >= 0 && z < DD && y >= 0 && y < HH && x >= 0 && x < WW)
            idx = tab[((c.x * DD + z) * HH + y) * WW + x];
        nbr[k * NV + i] = idx;
        k++;
    }
}

// ---- layer 1: one thread per voxel, acc[64] in VGPRs, scalar weights ----
__global__ __launch_bounds__(256) void k_layer1(
        const float* __restrict__ feats, const int* __restrict__ nbr,
        const float* __restrict__ w1, const float* __restrict__ b1,
        const float* __restrict__ g1, const float* __restrict__ be1,
        const float* __restrict__ m1, const float* __restrict__ v1,
        f16* __restrict__ x1) {
    int i = blockIdx.x * 256 + threadIdx.x;
    bool act = (i < NV);
    int ii = act ? i : 0;

    float acc[CD];
    #pragma unroll
    for (int c = 0; c < CD; c++) acc[c] = 0.f;

    #pragma unroll
    for (int k = 0; k < KOFF; k++) {
        int idx = act ? nbr[k * NV + ii] : -1;
        float fk = (idx >= 0) ? feats[idx] : 0.f;
        #pragma unroll
        for (int c = 0; c < CD; c++)
            acc[c] = fmaf(fk, w1[k * CD + c], acc[c]);
    }
    if (!act) return;

    #pragma unroll
    for (int c0 = 0; c0 < CD; c0 += 8) {
        f16x8 o;
        #pragma unroll
        for (int j = 0; j < 8; j++) {
            int c = c0 + j;
            float sc = g1[c] * rsqrtf(v1[c] + EPSV);
            float y = (acc[c] - m1[c] + b1[c]) * sc + be1[c];
            o[j] = (f16)fmaxf(y, 0.f);
        }
        *(f16x8*)(x1 + (size_t)i * CD + c0) = o;
    }
}

// ---- conv v5: wave-autonomous, ZERO barriers in the main loop.
// One wave (64 threads) per block; 64 voxels x 64 cout; private dbuf A-tile
// in LDS (2 x 8KB). Per iter k: [stage A(k+1) via GLDS using idx regs --
// compiler's vmcnt wait for those regs transitively guarantees A(k) landed]
// [load idx(k+2), B(k+1) to VGPRs] [ds_read A(k) lane-linear + MFMA].
// sched_barrier(0) pins phase order so ds_read can't hoist above the wait.
// LDS slot(row,chunk) = ks*2048 + vt*1024 + lane*16  (lane = g*32+ml,
// row = vt*32+ml, chunk = ks*2+g) -> both GLDS dest and frag reads lane-linear.
#define CONV_BODY(K, CUR, NXT)                                                  \
  {                                                                             \
    __builtin_amdgcn_sched_barrier(0);                                          \
    if ((K) + 1 < KOFF) {                                                       \
      _Pragma("unroll")                                                         \
      for (int ks = 0; ks < 4; ks++) {                                          \
        _Pragma("unroll")                                                       \
        for (int vt = 0; vt < 2; vt++) {                                        \
          int idx = idxN[vt];                                                   \
          const char* gp = (idx >= 0)                                           \
              ? (const char*)xin + (size_t)idx * 128 + (2 * ks + g) * 16        \
              : (const char*)zrow + (2 * ks + g) * 16;                          \
          char* lp = (char*)sA + (NXT) * 8192 + ks * 2048 + vt * 1024;          \
          GLDS16(gp, lp);                                                       \
        }                                                                       \
      }                                                                         \
    }                                                                           \
    __builtin_amdgcn_sched_barrier(0);                                          \
    if ((K) + 2 < KOFF) {                                                       \
      idxN[0] = nbr[(size_t)((K) + 2) * NV + i0];                               \
      idxN[1] = nbr[(size_t)((K) + 2) * NV + i1];                               \
    }                                                                           \
    if ((K) + 1 < KOFF) {                                                       \
      _Pragma("unroll")                                                         \
      for (int nt = 0; nt < 2; nt++)                                            \
        _Pragma("unroll")                                                       \
        for (int ks = 0; ks < 4; ks++)                                          \
          bB[NXT][nt][ks] = *(const f16x8*)(wT + (size_t)((K) + 1) * 4096       \
                                            + (ks * 2 + g) * 512                \
                                            + (nt * 32 + ml) * 8);              \
    }                                                                           \
    __builtin_amdgcn_sched_barrier(0);                                          \
    _Pragma("unroll")                                                           \
    for (int ks = 0; ks < 4; ks++) {                                            \
      f16x8 a0 = *(const f16x8*)((const char*)sA + (CUR) * 8192 + ks * 2048     \
                                 + lane * 16);                                  \
      f16x8 a1 = *(const f16x8*)((const char*)sA + (CUR) * 8192 + ks * 2048     \
                                 + 1024 + lane * 16);                           \
      _Pragma("unroll")                                                         \
      for (int nt = 0; nt < 2; nt++) {                                          \
        acc[0][nt] = __builtin_amdgcn_mfma_f32_32x32x16_f16(                    \
            a0, bB[CUR][nt][ks], acc[0][nt], 0, 0, 0);                          \
        acc[1][nt] = __builtin_amdgcn_mfma_f32_32x32x16_f16(                    \
            a1, bB[CUR][nt][ks], acc[1][nt], 0, 0, 0);                          \
      }                                                                         \
    }                                                                           \
  }

template <bool OUTF32>
__global__ __launch_bounds__(64, 3) void k_conv(
        const f16* __restrict__ xin, const f16* __restrict__ wT,
        const int* __restrict__ nbr, const f16* __restrict__ zrow,
        const float* __restrict__ bb, const float* __restrict__ gg,
        const float* __restrict__ bee, const float* __restrict__ mm,
        const float* __restrict__ vv, void* __restrict__ outp) {
    __shared__ __align__(16) unsigned char sA[16384];   // 2 x 8KB A-tile dbuf

    const int lane = threadIdx.x;
    const int g = lane >> 5;
    const int ml = lane & 31;
    const int vbase = blockIdx.x * 64;     // grid 6250, exact
    const int i0 = vbase + ml, i1 = i0 + 32;

    f32x16 acc[2][2];
    #pragma unroll
    for (int a = 0; a < 2; a++)
        #pragma unroll
        for (int b = 0; b < 2; b++) acc[a][b] = (f32x16)(0.f);

    f16x8 bB[2][2][4];
    int idxN[2];

    // prologue: A(0) -> buf0 (uses idx(0)); then idx(1); then B(0) -> bB[0]
    idxN[0] = nbr[i0];
    idxN[1] = nbr[i1];
    #pragma unroll
    for (int ks = 0; ks < 4; ks++) {
        #pragma unroll
        for (int vt = 0; vt < 2; vt++) {
            int idx = idxN[vt];
            const char* gp = (idx >= 0)
                ? (const char*)xin + (size_t)idx * 128 + (2 * ks + g) * 16
                : (const char*)zrow + (2 * ks + g) * 16;
            char* lp = (char*)sA + ks * 2048 + vt * 1024;
            GLDS16(gp, lp);
        }
    }
    __builtin_amdgcn_sched_barrier(0);
    idxN[0] = nbr[(size_t)NV + i0];
    idxN[1] = nbr[(size_t)NV + i1];
    #pragma unroll
    for (int nt = 0; nt < 2; nt++)
        #pragma unroll
        for (int ks = 0; ks < 4; ks++)
            bB[0][nt][ks] = *(const f16x8*)(wT + (ks * 2 + g) * 512
                                            + (nt * 32 + ml) * 8);

    // main loop: 13 unrolled pairs (k=0..25) + final k=26
    #pragma unroll 1
    for (int m = 0; m < 13; m++) {
        const int k0 = 2 * m;
        CONV_BODY(k0, 0, 1);
        CONV_BODY(k0 + 1, 1, 0);
    }
    CONV_BODY(26, 0, 1);

    // epilogue: BN+ReLU -> LDS (row-major) -> vectorized contiguous stores
    const int cn0 = ml, cn1 = 32 + ml;
    __syncthreads();
    #pragma unroll
    for (int nt = 0; nt < 2; nt++) {
        int cn = nt * 32 + ml;
        float sc = gg[cn] * rsqrtf(vv[cn] + EPSV);
        float sh = (bb[cn] - mm[cn]) * sc + bee[cn];
        #pragma unroll
        for (int vt = 0; vt < 2; vt++) {
            #pragma unroll
            for (int r = 0; r < 16; r++) {
                int row = vt * 32 + (r & 3) + 8 * (r >> 2) + 4 * g;
                float y = fmaxf(acc[vt][nt][r] * sc + sh, 0.f);
                if (OUTF32) *(float*)(sA + row * 256 + cn * 4) = y;
                else        *(f16*)(sA + row * 128 + cn * 2) = (f16)y;
            }
        }
    }
    __syncthreads();
    if (OUTF32) {
        char* gb = (char*)outp + (size_t)vbase * 256;   // 64 rows x 256B = 16KB
        #pragma unroll
        for (int it = 0; it < 16; it++) {
            int s = it * 64 + lane;
            *(float4*)(gb + s * 16) = *(const float4*)(sA + s * 16);
        }
    } else {
        char* gb = (char*)outp + (size_t)vbase * 128;   // 64 rows x 128B = 8KB
        #pragma unroll
        for (int it = 0; it < 8; it++) {
            int s = it * 64 + lane;
            *(float4*)(gb + s * 16) = *(const float4*)(sA + s * 16);
        }
    }
    (void)cn0; (void)cn1;
}

extern "C" void kernel_launch(void* const* d_in, const int* in_sizes, int n_in,
                              void* d_out, int out_size, void* d_ws, size_t ws_size,
                              hipStream_t stream) {
    (void)in_sizes; (void)n_in; (void)out_size; (void)ws_size;
    const float* feats = (const float*)d_in[0];
    const int4* coords = (const int4*)d_in[1];
    const float* w1 = (const float*)d_in[2];
    const float* b1 = (const float*)d_in[3];
    const float* g1 = (const float*)d_in[4];
    const float* be1 = (const float*)d_in[5];
    const float* m1 = (const float*)d_in[6];
    const float* v1 = (const float*)d_in[7];
    const float* w2 = (const float*)d_in[8];
    const float* b2 = (const float*)d_in[9];
    const float* g2 = (const float*)d_in[10];
    const float* be2 = (const float*)d_in[11];
    const float* m2 = (const float*)d_in[12];
    const float* v2 = (const float*)d_in[13];
    const float* w3 = (const float*)d_in[14];
    const float* b3 = (const float*)d_in[15];
    const float* g3 = (const float*)d_in[16];
    const float* be3 = (const float*)d_in[17];
    const float* m3 = (const float*)d_in[18];
    const float* v3 = (const float*)d_in[19];

    char* ws = (char*)d_ws;
    int* nbr  = (int*)(ws + OFF_NBR);
    f16* x1   = (f16*)(ws + OFF_X1);
    f16* x2   = (f16*)(ws + OFF_X2);
    int* tab  = (int*)(ws + OFF_TAB);
    f16* w2t  = (f16*)(ws + OFF_W2T);
    f16* w3t  = (f16*)(ws + OFF_W3T);
    f16* zrow = (f16*)(ws + OFF_ZERO);

    k_init<<<4096, 256, 0, stream>>>(w2, w3, tab, w2t, w3t, zrow);
    k_scatter<<<(NV + 255) / 256, 256, 0, stream>>>(coords, tab);
    k_nbr<<<(NV + 255) / 256, 256, 0, stream>>>(coords, tab, nbr);
    k_layer1<<<(NV + 255) / 256, 256, 0, stream>>>(feats, nbr, w1, b1, g1, be1, m1, v1, x1);
    const int convgrid = NV / 64;  // 6250, exact
    k_conv<false><<<convgrid, 64, 0, stream>>>(x1, w2t, nbr, zrow, b2, g2, be2, m2, v2, (void*)x2);
    k_conv<true><<<convgrid, 64, 0, stream>>>(x2, w3t, nbr, zrow, b3, g3, be3, m3, v3, d_out);
}

// Round 6
// 502.800 us; speedup vs baseline: 1.0915x; 1.0915x over previous
//
#include <hip/hip_runtime.h>

#define NV 400000
#define KOFF 27
#define CD 64
#define DD 128
#define HH 128
#define WW 128
#define TABN (2*DD*HH*WW)
#define EPSV 1e-5f

typedef _Float16 f16;
typedef _Float16 f16x8 __attribute__((ext_vector_type(8)));
typedef float f32x16 __attribute__((ext_vector_type(16)));

// ---- workspace layout (bytes) ----
#define OFF_NBR   0ull
#define OFF_X1    43200000ull
#define OFF_X2    94400000ull
#define OFF_TAB   94400000ull     // table dead before x2 written
#define OFF_W2T   145600000ull
#define OFF_W3T   145821184ull
#define OFF_ZERO  146042368ull

#define GLDS16(gp, lp) __builtin_amdgcn_global_load_lds( \
    (__attribute__((address_space(1))) void*)(gp), \
    (__attribute__((address_space(3))) void*)(lp), 16, 0, 0)

// ---- init: table=-1; weights -> f16 chunk-major wTg[k][cin/8][cout][cin&7] ----
__global__ void k_init(const float* __restrict__ w2, const float* __restrict__ w3,
                       int* __restrict__ tab, f16* __restrict__ w2t,
                       f16* __restrict__ w3t, f16* __restrict__ zrow) {
    int t = blockIdx.x * 256 + threadIdx.x;           // grid: 4096*256
    int4* tv = (int4*)tab;
    if (t < TABN / 4) tv[t] = make_int4(-1, -1, -1, -1);
    if (t < KOFF * CD * CD) {
        int k = t >> 12, r = t & 4095, c = r >> 6, ci = r & 63;
        int d = (k << 12) + ((ci >> 3) << 9) + (c << 3) + (ci & 7);
        w2t[d] = (f16)w2[(k << 12) + (ci << 6) + c];
        w3t[d] = (f16)w3[(k << 12) + (ci << 6) + c];
    }
    if (t < CD) zrow[t] = (f16)0.f;
}

__global__ void k_scatter(const int4* __restrict__ coords, int* __restrict__ tab) {
    int i = blockIdx.x * 256 + threadIdx.x;
    if (i >= NV) return;
    int4 c = coords[i];  // (b,z,y,x)
    int flat = ((c.x * DD + c.y) * HH + c.z) * WW + c.w;
    tab[flat] = i;
}

__global__ void k_nbr(const int4* __restrict__ coords, const int* __restrict__ tab,
                      int* __restrict__ nbr) {
    int i = blockIdx.x * 256 + threadIdx.x;
    if (i >= NV) return;
    int4 c = coords[i];
    int k = 0;
    #pragma unroll
    for (int dz = -1; dz <= 1; dz++)
    #pragma unroll
    for (int dy = -1; dy <= 1; dy++)
    #pragma unroll
    for (int dx = -1; dx <= 1; dx++) {
        int z = c.y + dz, y = c.z + dy, x = c.w + dx;
        int idx = -1;
        if (z >= 0 && z < DD && y >= 0 && y < HH && x >= 0 && x < WW)
            idx = tab[((c.x * DD + z) * HH + y) * WW + x];
        nbr[k * NV + i] = idx;
        k++;
    }
}

// ---- layer 1: one thread per voxel, acc[64] in VGPRs, scalar weights ----
__global__ __launch_bounds__(256) void k_layer1(
        const float* __restrict__ feats, const int* __restrict__ nbr,
        const float* __restrict__ w1, const float* __restrict__ b1,
        const float* __restrict__ g1, const float* __restrict__ be1,
        const float* __restrict__ m1, const float* __restrict__ v1,
        f16* __restrict__ x1) {
    int i = blockIdx.x * 256 + threadIdx.x;
    bool act = (i < NV);
    int ii = act ? i : 0;

    float acc[CD];
    #pragma unroll
    for (int c = 0; c < CD; c++) acc[c] = 0.f;

    #pragma unroll
    for (int k = 0; k < KOFF; k++) {
        int idx = act ? nbr[k * NV + ii] : -1;
        float fk = (idx >= 0) ? feats[idx] : 0.f;
        #pragma unroll
        for (int c = 0; c < CD; c++)
            acc[c] = fmaf(fk, w1[k * CD + c], acc[c]);
    }
    if (!act) return;

    #pragma unroll
    for (int c0 = 0; c0 < CD; c0 += 8) {
        f16x8 o;
        #pragma unroll
        for (int j = 0; j < 8; j++) {
            int c = c0 + j;
            float sc = g1[c] * rsqrtf(v1[c] + EPSV);
            float y = (acc[c] - m1[c] + b1[c]) * sc + be1[c];
            o[j] = (f16)fmaxf(y, 0.f);
        }
        *(f16x8*)(x1 + (size_t)i * CD + c0) = o;
    }
}

// ---- conv v6: lane-minimal gather-implicit-GEMM.
// Block 256 thr / 4 waves / 256 voxels. Per k:
//  - B(k): 8KB weight tile, GLDS-staged ONCE per block into LDS dbuf (2 instr/thr).
//  - A(k): per-lane 16B loads straight to VGPRs, PREDICATED on idx>=0 (masked
//    lanes issue no vmem request; ~87% of neighbors are inactive); invalid rows
//    zero-filled by v_mov. Double-buffered in regs, prefetched one k ahead.
//  - nbr: ONE wave-wide load (row=lane) + 2 ds_bpermute to distribute values,
//    prefetched two k ahead.
// One __syncthreads per k; its vmcnt drain is pre-covered by the MFMA phase.
#define MFMA3216(a, b, c) __builtin_amdgcn_mfma_f32_32x32x16_f16(a, b, c, 0, 0, 0)

#define CONV_BODY(K, CUR, NXT)                                                  \
  {                                                                             \
    __syncthreads();                                                            \
    __builtin_amdgcn_sched_barrier(0);                                          \
    if ((K) + 1 < KOFF) {                                                       \
      _Pragma("unroll")                                                         \
      for (int it = 0; it < 2; it++) {                                          \
        const char* gp = (const char*)wT + ((size_t)((K) + 1) * 8192            \
                          + it * 4096 + tid * 16);                              \
        char* lp = (char*)bbuf + (NXT) * 8192 + it * 4096 + wv * 1024;          \
        GLDS16(gp, lp);                                                         \
      }                                                                         \
      _Pragma("unroll")                                                         \
      for (int vt = 0; vt < 2; vt++) {                                          \
        int idx = (vt == 0) ? idxN0 : idxN1;                                    \
        if (idx >= 0) {                                                         \
          const char* ap = (const char*)xin + (size_t)idx * 128 + g * 16;       \
          _Pragma("unroll")                                                     \
          for (int ks = 0; ks < 4; ks++)                                        \
            aF[NXT][vt][ks] = *(const f16x8*)(ap + ks * 32);                    \
        } else {                                                                \
          _Pragma("unroll")                                                     \
          for (int ks = 0; ks < 4; ks++)                                        \
            aF[NXT][vt][ks] = (f16x8)(f16)0.f;                                  \
        }                                                                       \
      }                                                                         \
    }                                                                           \
    int iwN = -1;                                                               \
    if ((K) + 2 < KOFF) {                                                       \
      int rw = rowb + lane;                                                     \
      iwN = (rw < NV) ? nbr[(size_t)((K) + 2) * NV + rw] : -1;                  \
    }                                                                           \
    __builtin_amdgcn_sched_barrier(0);                                          \
    _Pragma("unroll")                                                           \
    for (int ks = 0; ks < 4; ks++) {                                            \
      const char* bp = (const char*)bbuf + (CUR) * 8192 + (2 * ks + g) * 1024;  \
      f16x8 b0 = *(const f16x8*)(bp + ml * 16);                                 \
      f16x8 b1 = *(const f16x8*)(bp + 512 + ml * 16);                           \
      acc[0][0] = MFMA3216(aF[CUR][0][ks], b0, acc[0][0]);                      \
      acc[0][1] = MFMA3216(aF[CUR][0][ks], b1, acc[0][1]);                      \
      acc[1][0] = MFMA3216(aF[CUR][1][ks], b0, acc[1][0]);                      \
      acc[1][1] = MFMA3216(aF[CUR][1][ks], b1, acc[1][1]);                      \
    }                                                                           \
    __builtin_amdgcn_sched_barrier(0);                                          \
    if ((K) + 2 < KOFF) {                                                       \
      idxN0 = __builtin_amdgcn_ds_bpermute(ml * 4, iwN);                        \
      idxN1 = __builtin_amdgcn_ds_bpermute((ml + 32) * 4, iwN);                 \
    }                                                                           \
  }

template <bool OUTF32>
__global__ __launch_bounds__(256, 3) void k_conv(
        const f16* __restrict__ xin, const f16* __restrict__ wT,
        const int* __restrict__ nbr,
        const float* __restrict__ bb, const float* __restrict__ gg,
        const float* __restrict__ bee, const float* __restrict__ mm,
        const float* __restrict__ vv, void* __restrict__ outp) {
    __shared__ __align__(16) unsigned char bbuf[2][8192];   // B dbuf, 16 KB
    __shared__ __align__(16) unsigned char sS[32768];       // epilogue scratch

    const int tid = threadIdx.x;
    const int lane = tid & 63;
    const int wv = tid >> 6;
    const int g = lane >> 5;
    const int ml = lane & 31;
    const int vbase = blockIdx.x * 256;       // grid 1563, last block partial
    const int rowb = vbase + wv * 64;

    f32x16 acc[2][2];
    #pragma unroll
    for (int a = 0; a < 2; a++)
        #pragma unroll
        for (int b = 0; b < 2; b++) acc[a][b] = (f32x16)(0.f);

    f16x8 aF[2][2][4];
    int idxN0, idxN1;

    // prologue: stage B(0); idx(0) -> load A(0) into aF[0]; idx(1) -> idxN
    #pragma unroll
    for (int it = 0; it < 2; it++) {
        const char* gp = (const char*)wT + ((size_t)it * 4096 + tid * 16);
        char* lp = (char*)bbuf + it * 4096 + wv * 1024;
        GLDS16(gp, lp);
    }
    {
        int rw = rowb + lane;
        int iw = (rw < NV) ? nbr[rw] : -1;
        idxN0 = __builtin_amdgcn_ds_bpermute(ml * 4, iw);
        idxN1 = __builtin_amdgcn_ds_bpermute((ml + 32) * 4, iw);
        #pragma unroll
        for (int vt = 0; vt < 2; vt++) {
            int idx = (vt == 0) ? idxN0 : idxN1;
            if (idx >= 0) {
                const char* ap = (const char*)xin + (size_t)idx * 128 + g * 16;
                #pragma unroll
                for (int ks = 0; ks < 4; ks++)
                    aF[0][vt][ks] = *(const f16x8*)(ap + ks * 32);
            } else {
                #pragma unroll
                for (int ks = 0; ks < 4; ks++)
                    aF[0][vt][ks] = (f16x8)(f16)0.f;
            }
        }
        int iw1 = (rw < NV) ? nbr[(size_t)NV + rw] : -1;
        idxN0 = __builtin_amdgcn_ds_bpermute(ml * 4, iw1);
        idxN1 = __builtin_amdgcn_ds_bpermute((ml + 32) * 4, iw1);
    }

    // 27 bodies: 13 pairs + final
    #pragma unroll 1
    for (int m = 0; m < 13; m++) {
        CONV_BODY(2 * m, 0, 1);
        CONV_BODY(2 * m + 1, 1, 0);
    }
    CONV_BODY(26, 0, 1);

    // epilogue: BN+ReLU -> LDS transpose -> vectorized stores (guarded)
    if (!OUTF32) {
        __syncthreads();
        #pragma unroll
        for (int nt = 0; nt < 2; nt++) {
            int cn = nt * 32 + ml;
            float sc = gg[cn] * rsqrtf(vv[cn] + EPSV);
            float sh = (bb[cn] - mm[cn]) * sc + bee[cn];
            #pragma unroll
            for (int vt = 0; vt < 2; vt++)
                #pragma unroll
                for (int r = 0; r < 16; r++) {
                    int rowl = wv * 64 + vt * 32 + (r & 3) + 8 * (r >> 2) + 4 * g;
                    float y = fmaxf(acc[vt][nt][r] * sc + sh, 0.f);
                    *(f16*)(sS + rowl * 128 + cn * 2) = (f16)y;
                }
        }
        __syncthreads();
        int nslot = (NV - vbase < 256 ? NV - vbase : 256) * 8;  // 16B slots
        char* gb = (char*)outp + (size_t)vbase * 128;
        #pragma unroll
        for (int it = 0; it < 8; it++) {
            int s = it * 256 + tid;
            if (s < nslot)
                *(float4*)(gb + s * 16) = *(const float4*)(sS + s * 16);
        }
    } else {
        #pragma unroll 1
        for (int p = 0; p < 2; p++) {
            __syncthreads();
            if ((wv >> 1) == p) {
                int lw = wv & 1;
                #pragma unroll
                for (int nt = 0; nt < 2; nt++) {
                    int cn = nt * 32 + ml;
                    float sc = gg[cn] * rsqrtf(vv[cn] + EPSV);
                    float sh = (bb[cn] - mm[cn]) * sc + bee[cn];
                    #pragma unroll
                    for (int vt = 0; vt < 2; vt++)
                        #pragma unroll
                        for (int r = 0; r < 16; r++) {
                            int rowl = lw * 64 + vt * 32 + (r & 3) + 8 * (r >> 2) + 4 * g;
                            float y = fmaxf(acc[vt][nt][r] * sc + sh, 0.f);
                            *(float*)(sS + rowl * 256 + cn * 4) = y;
                        }
                }
            }
            __syncthreads();
            char* gb = (char*)outp + ((size_t)vbase + p * 128) * 256;
            #pragma unroll
            for (int it = 0; it < 8; it++) {
                int s = it * 256 + tid;
                int gr = vbase + p * 128 + (s >> 4);
                if (gr < NV)
                    *(float4*)(gb + s * 16) = *(const float4*)(sS + s * 16);
            }
        }
    }
}

extern "C" void kernel_launch(void* const* d_in, const int* in_sizes, int n_in,
                              void* d_out, int out_size, void* d_ws, size_t ws_size,
                              hipStream_t stream) {
    (void)in_sizes; (void)n_in; (void)out_size; (void)ws_size;
    const float* feats = (const float*)d_in[0];
    const int4* coords = (const int4*)d_in[1];
    const float* w1 = (const float*)d_in[2];
    const float* b1 = (const float*)d_in[3];
    const float* g1 = (const float*)d_in[4];
    const float* be1 = (const float*)d_in[5];
    const float* m1 = (const float*)d_in[6];
    const float* v1 = (const float*)d_in[7];
    const float* w2 = (const float*)d_in[8];
    const float* b2 = (const float*)d_in[9];
    const float* g2 = (const float*)d_in[10];
    const float* be2 = (const float*)d_in[11];
    const float* m2 = (const float*)d_in[12];
    const float* v2 = (const float*)d_in[13];
    const float* w3 = (const float*)d_in[14];
    const float* b3 = (const float*)d_in[15];
    const float* g3 = (const float*)d_in[16];
    const float* be3 = (const float*)d_in[17];
    const float* m3 = (const float*)d_in[18];
    const float* v3 = (const float*)d_in[19];

    char* ws = (char*)d_ws;
    int* nbr  = (int*)(ws + OFF_NBR);
    f16* x1   = (f16*)(ws + OFF_X1);
    f16* x2   = (f16*)(ws + OFF_X2);
    int* tab  = (int*)(ws + OFF_TAB);
    f16* w2t  = (f16*)(ws + OFF_W2T);
    f16* w3t  = (f16*)(ws + OFF_W3T);
    f16* zrow = (f16*)(ws + OFF_ZERO);

    k_init<<<4096, 256, 0, stream>>>(w2, w3, tab, w2t, w3t, zrow);
    k_scatter<<<(NV + 255) / 256, 256, 0, stream>>>(coords, tab);
    k_nbr<<<(NV + 255) / 256, 256, 0, stream>>>(coords, tab, nbr);
    k_layer1<<<(NV + 255) / 256, 256, 0, stream>>>(feats, nbr, w1, b1, g1, be1, m1, v1, x1);
    const int convgrid = (NV + 255) / 256;  // 1563
    k_conv<false><<<convgrid, 256, 0, stream>>>(x1, w2t, nbr, b2, g2, be2, m2, v2, (void*)x2);
    k_conv<true><<<convgrid, 256, 0, stream>>>(x2, w3t, nbr, b3, g3, be3, m3, v3, d_out);
}